// Round 5
// baseline (10.213 us; speedup 1.0000x reference)
//
#include <hip/hip_runtime.h>
#include <hip/hip_bf16.h>

#define VOCAB 32000
#define EMBED 128
#define NTOK  (4 * 2048)
#define TV    64            // vocab columns per block
#define BLK   512           // 8 waves

// out[t][:] = W[:, e[t]] + bias.
// Per block (owns vocab range [v0, v0+64)):
//   1) each wave prefetches its 1024-id slice of e into 4 int4 registers,
//      and the lane's 2 bias values into a float2 register,
//   2) stages the [128][64] W tile LINEARLY into LDS via async
//      global_load_lds width=16 (4 instructions/wave, 1KB each — no VGPR
//      round-trip, no ds_writes, no transpose),
//   3) one barrier (compiler drains vmcnt(0)),
//   4) register ballot scan: each matched token's 512B row is emitted by the
//      whole wave (float2/lane, coalesced store). Emit LDS reads are 32-way
//      bank-conflicted (bank = c%32 for all d) but there are only ~2 emits
//      per wave — hundreds of cycles total, noise vs. the staging bytes.
__global__ __launch_bounds__(BLK) void embed_tile(const int* __restrict__ e,
                                                  const float* __restrict__ W,
                                                  const float* __restrict__ bias,
                                                  float* __restrict__ out) {
    __shared__ float lds[EMBED * TV];   // [d][c], 32 KB, NO padding (load_lds needs linear)

    const int tid  = threadIdx.x;
    const int lane = tid & 63;
    const int wid  = tid >> 6;              // 0..7
    const int v0   = blockIdx.x * TV;

    // (1) e-slice prefetch: wave wid owns ids [wid*1024, wid*1024+1024)
    const int wbase = wid << 10;
    int4 ebuf[4];
    #pragma unroll
    for (int s = 0; s < 4; ++s)
        ebuf[s] = *reinterpret_cast<const int4*>(&e[wbase + (s << 8) + (lane << 2)]);

    const float2 bl = *reinterpret_cast<const float2*>(&bias[lane << 1]);

    // (2) async stage: chunk k = wid*4+i is 1KB covering rows d=4k..4k+3.
    //     HW writes ldsbase + lane*16; lane's global src = W[d][v0+c], 16B contiguous.
    #pragma unroll
    for (int i = 0; i < 4; ++i) {
        const int k = (wid << 2) + i;
        const int d = (k << 2) + (lane >> 4);
        const int c = (lane & 15) << 2;
        __builtin_amdgcn_global_load_lds(
            (const __attribute__((address_space(1))) void*)(&W[d * VOCAB + v0 + c]),
            (__attribute__((address_space(3))) void*)(&lds[k << 8]),
            16, 0, 0);
    }
    __syncthreads();   // drains vmcnt(0): tile + ebuf ready

    // (4) ballot scan + cooperative emit
    const int l2 = lane << 1;
    #pragma unroll
    for (int s = 0; s < 4; ++s) {
        const int tok[4] = {ebuf[s].x, ebuf[s].y, ebuf[s].z, ebuf[s].w};
        #pragma unroll
        for (int j = 0; j < 4; ++j) {
            const unsigned c = (unsigned)(tok[j] - v0);
            unsigned long long m = __ballot(c < TV);
            while (m) {
                const int src = __builtin_ctzll(m);
                m &= m - 1;
                const int cc = __shfl((int)c, src, 64);
                const int tt = wbase + (s << 8) + (src << 2) + j;
                float2 v;
                v.x = lds[(l2 + 0) * TV + cc] + bl.x;
                v.y = lds[(l2 + 1) * TV + cc] + bl.y;
                *reinterpret_cast<float2*>(&out[tt * EMBED + l2]) = v;  // 512B/wave
            }
        }
    }
}

extern "C" void kernel_launch(void* const* d_in, const int* in_sizes, int n_in,
                              void* d_out, int out_size, void* d_ws, size_t ws_size,
                              hipStream_t stream) {
    const int*   e    = (const int*)d_in[0];
    const float* W    = (const float*)d_in[1];
    const float* bias = (const float*)d_in[2];
    float*       out  = (float*)d_out;

    const int grid = VOCAB / TV;   // 500 blocks
    embed_tile<<<grid, BLK, 0, stream>>>(e, W, bias, out);
}